// Round 9
// baseline (466.309 us; speedup 1.0000x reference)
//
#include <hip/hip_runtime.h>
#include <hip/hip_bf16.h>

#define NN    100000
#define KD    500
#define KP    512    // K padded (W zero-filled)
#define HID   64
#define LWS   264    // LDS row stride (bf16 elems) for a 256-wide K chunk
#define GPS   32     // gpk row stride in halfs: 64 B -> one cache line per node (both hops)
#define DB    32     // dst rows per bucket (100000 = 3125 * 32 exactly)
#define NB    3125   // NN / DB
#define CHUNK 2048   // edges per block in histogram/fill

typedef short frag8 __attribute__((ext_vector_type(8)));
typedef float f32x4 __attribute__((ext_vector_type(4)));

static __device__ __forceinline__ unsigned short f2b(float f) {
    return __builtin_bit_cast(unsigned short, __float2bfloat16(f));
}

// ---------------- Kernel 0: W1 fp32 -> bf16, zero-padded to K=512 ----------------
__global__ __launch_bounds__(256) void k0_w1bf(const float* __restrict__ W1,
                                               unsigned short* __restrict__ W1bf)
{
    const int i = blockIdx.x * 256 + threadIdx.x;   // 0..32767
    const int c = i >> 9;        // col 0..63
    const int k = i & 511;
    const float v = (k < KD) ? W1[c * KD + k] : 0.f;
    W1bf[i] = f2b(v);
}

// ---------------- Kernel 1: h = relu(x @ W1^T), bf16 MFMA ----------------
__global__ __launch_bounds__(256, 4) void k1_mfma(const float* __restrict__ x,
                                                  const unsigned short* __restrict__ W1bf,
                                                  float* __restrict__ h, int n)
{
    __shared__ unsigned short lw[64 * LWS];
    const int tid   = threadIdx.x;
    const int lane  = tid & 63;
    const int wid   = tid >> 6;
    const int l15   = lane & 15;
    const int l4    = lane >> 4;     // 0..3
    const int koffl = 8 * l4;        // lane's k sub-offset within a 32-k step

    const long rowBlk = (long)blockIdx.x * 64;
    long ra = rowBlk + wid * 16 + l15;
    if (ra >= n) ra = n - 1;                 // clamp; stores are guarded
    const float* xp = x + ra * KD + koffl;

    f32x4 acc[4] = {};
    const float4 z = make_float4(0.f, 0.f, 0.f, 0.f);

    for (int c = 0; c < 2; ++c) {
        if (c) __syncthreads();
        #pragma unroll
        for (int it = 0; it < 8; ++it) {
            const int idx = tid + it * 256;      // 0..2047
            const int r   = idx >> 5;            // 0..63
            const int q   = idx & 31;            // ushort8 index
            *(uint4*)&lw[r * LWS + q * 8] =
                *(const uint4*)&W1bf[r * KP + c * 256 + q * 8];
        }
        __syncthreads();

        int k0 = c * 256;
        float4 lo = (k0 + koffl     < KD) ? *(const float4*)(xp + k0)     : z;
        float4 hi = (k0 + koffl + 4 < KD) ? *(const float4*)(xp + k0 + 4) : z;

        #pragma unroll
        for (int ks = 0; ks < 8; ++ks) {
            float4 nlo = z, nhi = z;
            if (ks < 7) {
                const int kn = c * 256 + (ks + 1) * 32;
                nlo = (kn + koffl     < KD) ? *(const float4*)(xp + kn)     : z;
                nhi = (kn + koffl + 4 < KD) ? *(const float4*)(xp + kn + 4) : z;
            }
            frag8 a;
            a[0]=f2b(lo.x); a[1]=f2b(lo.y); a[2]=f2b(lo.z); a[3]=f2b(lo.w);
            a[4]=f2b(hi.x); a[5]=f2b(hi.y); a[6]=f2b(hi.z); a[7]=f2b(hi.w);
            const int koffw = ks * 32 + koffl;
            #pragma unroll
            for (int g = 0; g < 4; ++g) {
                const frag8 b = *(const frag8*)&lw[(g * 16 + l15) * LWS + koffw];
                acc[g] = __builtin_amdgcn_mfma_f32_16x16x32_bf16(a, b, acc[g], 0, 0, 0);
            }
            lo = nlo; hi = nhi;
        }
    }

    #pragma unroll
    for (int r = 0; r < 4; ++r) {
        const long row = rowBlk + wid * 16 + l4 * 4 + r;
        if (row < n) {
            #pragma unroll
            for (int g = 0; g < 4; ++g)
                h[row * HID + g * 16 + l15] = fmaxf(acc[g][r], 0.f);
        }
    }
}

// ---------------- Kernel 2: projections ----------------
// out = h @ WfA^T ; gpk[:,0:10) = fp16(h @ WfB^T) ; gpk[:,10:20) = fp16(h @ WfC^T)
__global__ __launch_bounds__(256) void k2_proj(const float* __restrict__ h,
                                               const float* __restrict__ Wf,
                                               float* __restrict__ out,
                                               _Float16* __restrict__ gpk, int n)
{
    __shared__ float lwf[10 * 196];
    const int tid = threadIdx.x;
    for (int idx = tid; idx < 480; idx += 256) {
        const int j = idx / 48;
        const int q = idx - j * 48;
        const float4 v = *(const float4*)&Wf[j * 192 + 4 * q];
        *(float4*)&lwf[j * 196 + 4 * q] = v;
    }
    __syncthreads();

    const long row = (long)blockIdx.x * 8 + (tid >> 5);
    const int  j   = tid & 31;
    if (row < n && j < 30) {
        const int wrow = (j < 10) ? j : ((j < 20) ? j - 10 : j - 20);
        const int coff = (j < 10) ? 0 : ((j < 20) ? 64 : 128);
        const float* wp = &lwf[wrow * 196 + coff];
        const float* hp = &h[row * HID];
        float s = 0.f;
        #pragma unroll
        for (int q = 0; q < 16; ++q) {
            const float4 hv = *(const float4*)&hp[4 * q];
            const float4 wv = *(const float4*)&wp[4 * q];
            s += hv.x * wv.x + hv.y * wv.y + hv.z * wv.z + hv.w * wv.w;
        }
        if (j < 10)      out[row * 10 + j] = s;
        else if (j < 20) gpk[row * GPS + (j - 10)]      = (_Float16)s;
        else             gpk[row * GPS + 10 + (j - 20)] = (_Float16)s;
    }
}

// ---------------- Kernel A: per-(chunk,bucket) edge histogram ----------------
// Cmat layout [chunk][bucket] -> coalesced writes here, coalesced reads in kC/kS1.
__global__ __launch_bounds__(256) void kA_hist(const int* __restrict__ dst1, int nnz1,
                                               const int* __restrict__ dst2, int ntE,
                                               int* __restrict__ Cmat)
{
    __shared__ int cnt[NB];
    const int tid = threadIdx.x, blk = blockIdx.x;
    for (int i = tid; i < NB; i += 256) cnt[i] = 0;
    __syncthreads();
    const int base = blk * CHUNK;
    #pragma unroll
    for (int it = 0; it < CHUNK / 256; ++it) {
        const int id = base + it * 256 + tid;
        if (id < ntE) {
            const int d = (id < nnz1) ? dst1[id] : dst2[id - nnz1];
            atomicAdd(&cnt[d / DB], 1);
        }
    }
    __syncthreads();
    for (int b = tid; b < NB; b += 256) Cmat[(size_t)blk * NB + b] = cnt[b];
}

// ---------------- Kernel S1: column scan — thread owns a bucket, loops chunks ----
__global__ __launch_bounds__(256) void kS1_colscan(const int* __restrict__ Cmat, int nblk,
                                                   int* __restrict__ OFFmat,
                                                   int* __restrict__ rowSum)
{
    const int b = blockIdx.x * 256 + threadIdx.x;
    if (b >= NB) return;
    int run = 0;
    for (int c = 0; c < nblk; ++c) {
        const int v = Cmat[(size_t)c * NB + b];     // coalesced across threads
        OFFmat[(size_t)c * NB + b] = run;
        run += v;
    }
    rowSum[b] = run;
}

// ---------------- Kernel S2: exclusive scan of bucket totals (13 elems/thread) --
__global__ __launch_bounds__(256) void kS2_basescan(const int* __restrict__ rowSum,
                                                    int* __restrict__ rowBase)
{
    __shared__ int ls[256];
    const int tid = threadIdx.x;
    const int EPT = (NB + 255) / 256;   // 13
    int e[13]; int s = 0;
    #pragma unroll
    for (int u = 0; u < 13; ++u) {
        const int i = tid * EPT + u;
        e[u] = (i < NB) ? rowSum[i] : 0;
        s += e[u];
    }
    ls[tid] = s;
    __syncthreads();
    for (int off = 1; off < 256; off <<= 1) {
        const int v = (tid >= off) ? ls[tid - off] : 0;
        __syncthreads();
        ls[tid] += v;
        __syncthreads();
    }
    int run = ls[tid] - s;
    #pragma unroll
    for (int u = 0; u < 13; ++u) {
        const int i = tid * EPT + u;
        if (i < NB) rowBase[i] = run;
        run += e[u];
    }
}

// ---------------- Kernel C: fill buckets with packed edge records ----------------
// rec.x = src | hop<<17 | dstLocal<<18 ; rec.y = bitcast(val)
__global__ __launch_bounds__(256) void kC_fill(const int* __restrict__ src1,
                                               const int* __restrict__ dst1,
                                               const float* __restrict__ val1, int nnz1,
                                               const int* __restrict__ src2,
                                               const int* __restrict__ dst2,
                                               const float* __restrict__ val2, int ntE,
                                               const int* __restrict__ OFFmat,
                                               const int* __restrict__ rowBase,
                                               uint2* __restrict__ bins)
{
    __shared__ int cur[NB];
    const int tid = threadIdx.x, blk = blockIdx.x;
    for (int b = tid; b < NB; b += 256)
        cur[b] = rowBase[b] + OFFmat[(size_t)blk * NB + b];
    __syncthreads();
    const int base = blk * CHUNK;
    #pragma unroll
    for (int it = 0; it < CHUNK / 256; ++it) {
        const int id = base + it * 256 + tid;
        if (id < ntE) {
            const bool h1 = id < nnz1;
            const int  ii = h1 ? id : id - nnz1;
            const int   s = h1 ? src1[ii] : src2[ii];
            const int   d = h1 ? dst1[ii] : dst2[ii];
            const float v = h1 ? val1[ii] : val2[ii];
            const int   b = d / DB;
            const int slot = atomicAdd(&cur[b], 1);
            uint2 r;
            r.x = (unsigned)s | ((unsigned)(!h1) << 17) | ((unsigned)(d - b * DB) << 18);
            r.y = __builtin_bit_cast(unsigned, v);
            bins[slot] = r;
        }
    }
}

// ---------------- Kernel D: per-bucket LDS accumulate, ILP-8, fp16 packed gather -
__global__ __launch_bounds__(256) void kD_acc(const uint2* __restrict__ bins,
                                              const int* __restrict__ rowBase,
                                              const int* __restrict__ rowSum,
                                              const _Float16* __restrict__ gpk,
                                              float* __restrict__ out)
{
    __shared__ float lacc[DB * 10];
    const int tid = threadIdx.x, b = blockIdx.x;
    for (int i = tid; i < DB * 10; i += 256) lacc[i] = 0.f;
    __syncthreads();
    const int start = rowBase[b];
    const int nt    = rowSum[b] * 10;
    for (int i0 = tid; i0 < nt; i0 += 2048) {
        float c[8]; int li[8];
        #pragma unroll
        for (int u = 0; u < 8; ++u) {
            const int i = i0 + u * 256;
            li[u] = -1;
            c[u] = 0.f;
            if (i < nt) {
                const int e = (int)((unsigned)i / 10u);
                const int j = i - 10 * e;
                const uint2 r = bins[start + e];
                const int   src = r.x & 0x1FFFF;
                const int   hop = (r.x >> 17) & 1;
                c[u]  = __builtin_bit_cast(float, r.y)
                        * (float)gpk[(size_t)src * GPS + hop * 10 + j];
                li[u] = (int)(r.x >> 18) * 10 + j;
            }
        }
        #pragma unroll
        for (int u = 0; u < 8; ++u)
            if (li[u] >= 0) atomicAdd(&lacc[li[u]], c[u]);
    }
    __syncthreads();
    float* op = out + (size_t)b * DB * 10;
    for (int i = tid; i < DB * 10; i += 256)
        op[i] += lacc[i];
}

// ---------------- Fallback: direct scatter (agent-scope atomics) ----------------
__global__ __launch_bounds__(256) void k_scatter_dir(const int* __restrict__ src1,
                                                     const int* __restrict__ dst1,
                                                     const float* __restrict__ val1, int n1,
                                                     const int* __restrict__ src2,
                                                     const int* __restrict__ dst2,
                                                     const float* __restrict__ val2, int nt,
                                                     const _Float16* __restrict__ gpk,
                                                     float* __restrict__ out)
{
    const int t = blockIdx.x * 256 + threadIdx.x;
    if (t >= nt) return;
    const bool h1 = t < n1;
    const int  tt = h1 ? t : t - n1;
    const int  e  = (int)((unsigned)tt / 10u);
    const int  j  = tt - 10 * e;
    const int* sp = h1 ? src1 : src2;
    const int* dp = h1 ? dst1 : dst2;
    const float* vp = h1 ? val1 : val2;
    unsafeAtomicAdd(&out[(size_t)dp[e] * 10 + j],
                    vp[e] * (float)gpk[(size_t)sp[e] * GPS + (h1 ? 0 : 10) + j]);
}

extern "C" void kernel_launch(void* const* d_in, const int* in_sizes, int n_in,
                              void* d_out, int out_size, void* d_ws, size_t ws_size,
                              hipStream_t stream)
{
    const float* x    = (const float*)d_in[0];
    const float* W1   = (const float*)d_in[1];
    const float* Wf   = (const float*)d_in[2];
    const int*   src1 = (const int*)d_in[3];
    const int*   dst1 = (const int*)d_in[4];
    const float* val1 = (const float*)d_in[5];
    const int*   src2 = (const int*)d_in[6];
    const int*   dst2 = (const int*)d_in[7];
    const float* val2 = (const float*)d_in[8];
    const int nnz1 = in_sizes[3];
    const int nnz2 = in_sizes[6];
    const int ntE  = nnz1 + nnz2;
    const int n = NN;
    const int nblk = (ntE + CHUNK - 1) / CHUNK;

    char* p = (char*)d_ws;
    unsigned short* W1bf = (unsigned short*)p;       p += (size_t)64 * KP * 2;   // 64 KB
    float* h      = (float*)p;                       p += (size_t)NN * HID * 4;  // 25.6 MB
    _Float16* gpk = (_Float16*)p;                    p += (size_t)NN * GPS * 2;  //  6.4 MB
    uint2* bins   = (uint2*)p;                       p += (size_t)ntE * 8;       // 14.4 MB
    int* Cmat     = (int*)p;                         p += (size_t)NB * nblk * 4; // 11.0 MB
    int* OFFmat   = (int*)p;                         p += (size_t)NB * nblk * 4; // 11.0 MB
    int* rowSum   = (int*)p;                         p += (size_t)NB * 4;
    int* rowBase  = (int*)p;                         p += (size_t)NB * 4;
    float* out    = (float*)d_out;                   // [NN][10]
    const size_t ws_need = (size_t)(p - (char*)d_ws);

    k0_w1bf<<<128, 256, 0, stream>>>(W1, W1bf);
    k1_mfma<<<(n + 63) / 64, 256, 0, stream>>>(x, W1bf, h, n);
    k2_proj<<<(n + 7) / 8, 256, 0, stream>>>(h, Wf, out, gpk, n);

    if (ws_size >= ws_need) {
        kA_hist<<<nblk, 256, 0, stream>>>(dst1, nnz1, dst2, ntE, Cmat);
        kS1_colscan<<<(NB + 255) / 256, 256, 0, stream>>>(Cmat, nblk, OFFmat, rowSum);
        kS2_basescan<<<1, 256, 0, stream>>>(rowSum, rowBase);
        kC_fill<<<nblk, 256, 0, stream>>>(src1, dst1, val1, nnz1,
                                          src2, dst2, val2, ntE,
                                          OFFmat, rowBase, bins);
        kD_acc<<<NB, 256, 0, stream>>>(bins, rowBase, rowSum, gpk, out);
    } else {
        const int n1 = 10 * nnz1;
        const int nt = n1 + 10 * nnz2;
        k_scatter_dir<<<(nt + 255) / 256, 256, 0, stream>>>(src1, dst1, val1, n1,
                                                            src2, dst2, val2, nt,
                                                            gpk, out);
    }
}

// Round 11
// 307.823 us; speedup vs baseline: 1.5149x; 1.5149x over previous
//
#include <hip/hip_runtime.h>
#include <hip/hip_bf16.h>

#define NN    100000
#define KD    500
#define KP    512    // K padded (W zero-filled)
#define HID   64
#define LWS   264    // LDS row stride (bf16 elems) for a 256-wide K chunk
#define GPS   20     // gpk row stride in halfs: 40 B/node, 4 MB total -> L2-resident
#define DB    32     // dst rows per bucket (100000 = 3125 * 32 exactly)
#define NB    3125   // NN / DB
#define CHUNK 2048   // edges per block in histogram/fill

typedef short frag8 __attribute__((ext_vector_type(8)));
typedef float f32x4 __attribute__((ext_vector_type(4)));
typedef unsigned long long u64;

static __device__ __forceinline__ unsigned short f2b(float f) {
    return __builtin_bit_cast(unsigned short, __float2bfloat16(f));
}

// ---------------- Kernel 0: W1 fp32 -> bf16, zero-padded to K=512 ----------------
__global__ __launch_bounds__(256) void k0_w1bf(const float* __restrict__ W1,
                                               unsigned short* __restrict__ W1bf)
{
    const int i = blockIdx.x * 256 + threadIdx.x;   // 0..32767
    const int c = i >> 9;        // col 0..63
    const int k = i & 511;
    const float v = (k < KD) ? W1[c * KD + k] : 0.f;
    W1bf[i] = f2b(v);
}

// ---------------- Kernel 1: h = relu(x @ W1^T), bf16 MFMA ----------------
// 512 threads = 8 waves; each wave computes 16 rows x 64 cols; block = 128 rows.
__global__ __launch_bounds__(512, 6) void k1_mfma(const float* __restrict__ x,
                                                  const unsigned short* __restrict__ W1bf,
                                                  float* __restrict__ h, int n)
{
    __shared__ unsigned short lw[64 * LWS];
    const int tid   = threadIdx.x;
    const int lane  = tid & 63;
    const int wid   = tid >> 6;      // 0..7
    const int l15   = lane & 15;
    const int l4    = lane >> 4;     // 0..3
    const int koffl = 8 * l4;        // lane's k sub-offset within a 32-k step

    const long rowBlk = (long)blockIdx.x * 128;
    long ra = rowBlk + wid * 16 + l15;
    if (ra >= n) ra = n - 1;                 // clamp; stores are guarded
    const float* xp = x + ra * KD + koffl;

    f32x4 acc[4] = {};
    const float4 z = make_float4(0.f, 0.f, 0.f, 0.f);

    for (int c = 0; c < 2; ++c) {
        if (c) __syncthreads();
        // stage W1bf[64][c*256 .. +256) -> lw (16B copies)
        #pragma unroll
        for (int it = 0; it < 4; ++it) {
            const int idx = tid + it * 512;      // 0..2047
            const int r   = idx >> 5;            // 0..63
            const int q   = idx & 31;            // ushort8 index
            *(uint4*)&lw[r * LWS + q * 8] =
                *(const uint4*)&W1bf[r * KP + c * 256 + q * 8];
        }
        __syncthreads();

        int k0 = c * 256;
        float4 lo = (k0 + koffl     < KD) ? *(const float4*)(xp + k0)     : z;
        float4 hi = (k0 + koffl + 4 < KD) ? *(const float4*)(xp + k0 + 4) : z;

        #pragma unroll
        for (int ks = 0; ks < 8; ++ks) {
            float4 nlo = z, nhi = z;
            if (ks < 7) {
                const int kn = c * 256 + (ks + 1) * 32;
                nlo = (kn + koffl     < KD) ? *(const float4*)(xp + kn)     : z;
                nhi = (kn + koffl + 4 < KD) ? *(const float4*)(xp + kn + 4) : z;
            }
            frag8 a;
            a[0]=f2b(lo.x); a[1]=f2b(lo.y); a[2]=f2b(lo.z); a[3]=f2b(lo.w);
            a[4]=f2b(hi.x); a[5]=f2b(hi.y); a[6]=f2b(hi.z); a[7]=f2b(hi.w);
            const int koffw = ks * 32 + koffl;
            #pragma unroll
            for (int g = 0; g < 4; ++g) {
                const frag8 b = *(const frag8*)&lw[(g * 16 + l15) * LWS + koffw];
                acc[g] = __builtin_amdgcn_mfma_f32_16x16x32_bf16(a, b, acc[g], 0, 0, 0);
            }
            lo = nlo; hi = nhi;
        }
    }

    #pragma unroll
    for (int r = 0; r < 4; ++r) {
        const long row = rowBlk + wid * 16 + l4 * 4 + r;
        if (row < n) {
            #pragma unroll
            for (int g = 0; g < 4; ++g)
                h[row * HID + g * 16 + l15] = fmaxf(acc[g][r], 0.f);
        }
    }
}

// ---------------- Kernel 2: projections ----------------
// out = h @ WfA^T ; gpk[:,0:10) = fp16(h @ WfB^T) ; gpk[:,10:20) = fp16(h @ WfC^T)
__global__ __launch_bounds__(256) void k2_proj(const float* __restrict__ h,
                                               const float* __restrict__ Wf,
                                               float* __restrict__ out,
                                               _Float16* __restrict__ gpk, int n)
{
    __shared__ float lwf[10 * 196];
    const int tid = threadIdx.x;
    for (int idx = tid; idx < 480; idx += 256) {
        const int j = idx / 48;
        const int q = idx - j * 48;
        const float4 v = *(const float4*)&Wf[j * 192 + 4 * q];
        *(float4*)&lwf[j * 196 + 4 * q] = v;
    }
    __syncthreads();

    const long row = (long)blockIdx.x * 8 + (tid >> 5);
    const int  j   = tid & 31;
    if (row < n && j < 30) {
        const int wrow = (j < 10) ? j : ((j < 20) ? j - 10 : j - 20);
        const int coff = (j < 10) ? 0 : ((j < 20) ? 64 : 128);
        const float* wp = &lwf[wrow * 196 + coff];
        const float* hp = &h[row * HID];
        float s = 0.f;
        #pragma unroll
        for (int q = 0; q < 16; ++q) {
            const float4 hv = *(const float4*)&hp[4 * q];
            const float4 wv = *(const float4*)&wp[4 * q];
            s += hv.x * wv.x + hv.y * wv.y + hv.z * wv.z + hv.w * wv.w;
        }
        if (j < 10)      out[row * 10 + j] = s;
        else if (j < 20) gpk[row * GPS + (j - 10)]      = (_Float16)s;
        else             gpk[row * GPS + 10 + (j - 20)] = (_Float16)s;
    }
}

// ---------------- Kernel A: per-(chunk,bucket) edge histogram ----------------
__global__ __launch_bounds__(256) void kA_hist(const int* __restrict__ dst1, int nnz1,
                                               const int* __restrict__ dst2, int ntE,
                                               int* __restrict__ Cmat)
{
    __shared__ int cnt[NB];
    const int tid = threadIdx.x, blk = blockIdx.x;
    for (int i = tid; i < NB; i += 256) cnt[i] = 0;
    __syncthreads();
    const int base = blk * CHUNK;
    #pragma unroll
    for (int it = 0; it < CHUNK / 256; ++it) {
        const int id = base + it * 256 + tid;
        if (id < ntE) {
            const int d = (id < nnz1) ? __builtin_nontemporal_load(&dst1[id])
                                      : __builtin_nontemporal_load(&dst2[id - nnz1]);
            atomicAdd(&cnt[d / DB], 1);
        }
    }
    __syncthreads();
    for (int b = tid; b < NB; b += 256) Cmat[(size_t)blk * NB + b] = cnt[b];
}

// ---------------- Kernel S1: grouped bucket scan ----------------
// 16 buckets/block x 16 threads/bucket; lanes span 16 consecutive buckets ->
// coalesced loads. Slot order within a bucket is arbitrary (kD only sums).
__global__ __launch_bounds__(256) void kS1_grp(const int* __restrict__ Cmat, int nblk,
                                               int* __restrict__ OFFmat,
                                               int* __restrict__ rowSum)
{
    __shared__ int lsum[256];
    const int tid = threadIdx.x;
    const int g   = tid >> 4;                  // group 0..15
    const int t   = tid & 15;                  // lane in group
    const int b   = blockIdx.x * 16 + g;       // bucket
    int s = 0;
    if (b < NB)
        for (int c = t; c < nblk; c += 16)
            s += Cmat[(size_t)c * NB + b];
    lsum[tid] = s;
    __syncthreads();
    int pre = 0;
    #pragma unroll
    for (int u = 0; u < 16; ++u) {
        const int v = lsum[(g << 4) + u];
        if (u < t) pre += v;
    }
    if (b < NB) {
        int run = pre;
        for (int c = t; c < nblk; c += 16) {
            OFFmat[(size_t)c * NB + b] = run;
            run += Cmat[(size_t)c * NB + b];
        }
        if (t == 15) rowSum[b] = run;
    }
}

// ---------------- Kernel S2: exclusive scan of bucket totals (13 elems/thread) --
__global__ __launch_bounds__(256) void kS2_basescan(const int* __restrict__ rowSum,
                                                    int* __restrict__ rowBase)
{
    __shared__ int ls[256];
    const int tid = threadIdx.x;
    const int EPT = (NB + 255) / 256;   // 13
    int e[13]; int s = 0;
    #pragma unroll
    for (int u = 0; u < 13; ++u) {
        const int i = tid * EPT + u;
        e[u] = (i < NB) ? rowSum[i] : 0;
        s += e[u];
    }
    ls[tid] = s;
    __syncthreads();
    for (int off = 1; off < 256; off <<= 1) {
        const int v = (tid >= off) ? ls[tid - off] : 0;
        __syncthreads();
        ls[tid] += v;
        __syncthreads();
    }
    int run = ls[tid] - s;
    #pragma unroll
    for (int u = 0; u < 13; ++u) {
        const int i = tid * EPT + u;
        if (i < NB) rowBase[i] = run;
        run += e[u];
    }
}

// ---------------- Kernel C: fill buckets with packed edge records ----------------
// rec = (src | hop<<17 | dstLocal<<18) | bitcast(val)<<32  -- one u64 store
__global__ __launch_bounds__(256) void kC_fill(const int* __restrict__ src1,
                                               const int* __restrict__ dst1,
                                               const float* __restrict__ val1, int nnz1,
                                               const int* __restrict__ src2,
                                               const int* __restrict__ dst2,
                                               const float* __restrict__ val2, int ntE,
                                               const int* __restrict__ OFFmat,
                                               const int* __restrict__ rowBase,
                                               u64* __restrict__ bins)
{
    __shared__ int cur[NB];
    const int tid = threadIdx.x, blk = blockIdx.x;
    for (int b = tid; b < NB; b += 256)
        cur[b] = rowBase[b] + OFFmat[(size_t)blk * NB + b];
    __syncthreads();
    const int base = blk * CHUNK;
    #pragma unroll
    for (int it = 0; it < CHUNK / 256; ++it) {
        const int id = base + it * 256 + tid;
        if (id < ntE) {
            const bool h1 = id < nnz1;
            const int  ii = h1 ? id : id - nnz1;
            const int   s = h1 ? __builtin_nontemporal_load(&src1[ii])
                               : __builtin_nontemporal_load(&src2[ii]);
            const int   d = h1 ? __builtin_nontemporal_load(&dst1[ii])
                               : __builtin_nontemporal_load(&dst2[ii]);
            const float v = h1 ? __builtin_nontemporal_load(&val1[ii])
                               : __builtin_nontemporal_load(&val2[ii]);
            const int   b = d / DB;
            const int slot = atomicAdd(&cur[b], 1);
            const unsigned lo = (unsigned)s | ((unsigned)(!h1) << 17)
                              | ((unsigned)(d - b * DB) << 18);
            const u64 r = (u64)lo | ((u64)__builtin_bit_cast(unsigned, v) << 32);
            __builtin_nontemporal_store(r, &bins[slot]);
        }
    }
}

// ---------------- Kernel D: per-bucket LDS accumulate, ILP-8, L2-resident gather -
__global__ __launch_bounds__(256) void kD_acc(const u64* __restrict__ bins,
                                              const int* __restrict__ rowBase,
                                              const int* __restrict__ rowSum,
                                              const _Float16* __restrict__ gpk,
                                              float* __restrict__ out)
{
    __shared__ float lacc[DB * 10];
    const int tid = threadIdx.x, b = blockIdx.x;
    for (int i = tid; i < DB * 10; i += 256) lacc[i] = 0.f;
    __syncthreads();
    const int start = rowBase[b];
    const int nt    = rowSum[b] * 10;
    for (int i0 = tid; i0 < nt; i0 += 2048) {
        float c[8]; int li[8];
        #pragma unroll
        for (int u = 0; u < 8; ++u) {
            const int i = i0 + u * 256;
            li[u] = -1;
            c[u] = 0.f;
            if (i < nt) {
                const int e = (int)((unsigned)i / 10u);
                const int j = i - 10 * e;
                const u64 r = __builtin_nontemporal_load(&bins[start + e]);
                const unsigned lo = (unsigned)r;
                const int   src = lo & 0x1FFFF;
                const int   hop = (lo >> 17) & 1;
                const float v   = __builtin_bit_cast(float, (unsigned)(r >> 32));
                c[u]  = v * (float)gpk[(size_t)src * GPS + hop * 10 + j];
                li[u] = (int)(lo >> 18) * 10 + j;
            }
        }
        #pragma unroll
        for (int u = 0; u < 8; ++u)
            if (li[u] >= 0) atomicAdd(&lacc[li[u]], c[u]);
    }
    __syncthreads();
    float* op = out + (size_t)b * DB * 10;
    for (int i = tid; i < DB * 10; i += 256) {
        const float v = __builtin_nontemporal_load(&op[i]) + lacc[i];
        __builtin_nontemporal_store(v, &op[i]);
    }
}

// ---------------- Fallback: direct scatter (agent-scope atomics) ----------------
__global__ __launch_bounds__(256) void k_scatter_dir(const int* __restrict__ src1,
                                                     const int* __restrict__ dst1,
                                                     const float* __restrict__ val1, int n1,
                                                     const int* __restrict__ src2,
                                                     const int* __restrict__ dst2,
                                                     const float* __restrict__ val2, int nt,
                                                     const _Float16* __restrict__ gpk,
                                                     float* __restrict__ out)
{
    const int t = blockIdx.x * 256 + threadIdx.x;
    if (t >= nt) return;
    const bool h1 = t < n1;
    const int  tt = h1 ? t : t - n1;
    const int  e  = (int)((unsigned)tt / 10u);
    const int  j  = tt - 10 * e;
    const int* sp = h1 ? src1 : src2;
    const int* dp = h1 ? dst1 : dst2;
    const float* vp = h1 ? val1 : val2;
    unsafeAtomicAdd(&out[(size_t)dp[e] * 10 + j],
                    vp[e] * (float)gpk[(size_t)sp[e] * GPS + (h1 ? 0 : 10) + j]);
}

extern "C" void kernel_launch(void* const* d_in, const int* in_sizes, int n_in,
                              void* d_out, int out_size, void* d_ws, size_t ws_size,
                              hipStream_t stream)
{
    const float* x    = (const float*)d_in[0];
    const float* W1   = (const float*)d_in[1];
    const float* Wf   = (const float*)d_in[2];
    const int*   src1 = (const int*)d_in[3];
    const int*   dst1 = (const int*)d_in[4];
    const float* val1 = (const float*)d_in[5];
    const int*   src2 = (const int*)d_in[6];
    const int*   dst2 = (const int*)d_in[7];
    const float* val2 = (const float*)d_in[8];
    const int nnz1 = in_sizes[3];
    const int nnz2 = in_sizes[6];
    const int ntE  = nnz1 + nnz2;
    const int n = NN;
    const int nblk = (ntE + CHUNK - 1) / CHUNK;

    char* p = (char*)d_ws;
    unsigned short* W1bf = (unsigned short*)p;       p += (size_t)64 * KP * 2;   // 64 KB
    float* h      = (float*)p;                       p += (size_t)NN * HID * 4;  // 25.6 MB
    _Float16* gpk = (_Float16*)p;                    p += (size_t)NN * GPS * 2;  //  4.0 MB
    u64* bins     = (u64*)p;                         p += (size_t)ntE * 8;       // 14.4 MB
    int* Cmat     = (int*)p;                         p += (size_t)NB * nblk * 4; // 11.0 MB
    int* OFFmat   = (int*)p;                         p += (size_t)NB * nblk * 4; // 11.0 MB
    int* rowSum   = (int*)p;                         p += (size_t)NB * 4;
    int* rowBase  = (int*)p;                         p += (size_t)NB * 4;
    float* out    = (float*)d_out;                   // [NN][10]
    const size_t ws_need = (size_t)(p - (char*)d_ws);

    k0_w1bf<<<128, 256, 0, stream>>>(W1, W1bf);
    k1_mfma<<<(n + 127) / 128, 512, 0, stream>>>(x, W1bf, h, n);
    k2_proj<<<(n + 7) / 8, 256, 0, stream>>>(h, Wf, out, gpk, n);

    if (ws_size >= ws_need) {
        kA_hist<<<nblk, 256, 0, stream>>>(dst1, nnz1, dst2, ntE, Cmat);
        kS1_grp<<<(NB + 15) / 16, 256, 0, stream>>>(Cmat, nblk, OFFmat, rowSum);
        kS2_basescan<<<1, 256, 0, stream>>>(rowSum, rowBase);
        kC_fill<<<nblk, 256, 0, stream>>>(src1, dst1, val1, nnz1,
                                          src2, dst2, val2, ntE,
                                          OFFmat, rowBase, bins);
        kD_acc<<<NB, 256, 0, stream>>>(bins, rowBase, rowSum, gpk, out);
    } else {
        const int n1 = 10 * nnz1;
        const int nt = n1 + 10 * nnz2;
        k_scatter_dir<<<(nt + 255) / 256, 256, 0, stream>>>(src1, dst1, val1, n1,
                                                            src2, dst2, val2, nt,
                                                            gpk, out);
    }
}

// Round 12
// 281.145 us; speedup vs baseline: 1.6586x; 1.0949x over previous
//
#include <hip/hip_runtime.h>
#include <hip/hip_bf16.h>

#define NN    100000
#define KD    500
#define KP    512    // K padded (W zero-filled)
#define HID   64
#define LWS   264    // LDS row stride (bf16 elems) for a 256-wide K chunk
#define GPS   20     // gpk row stride in halfs: 40 B/node, 4 MB total -> L2-resident
#define DB    32     // dst rows per bucket (100000 = 3125 * 32 exactly)
#define NB    3125   // NN / DB
#define CHUNK 4096   // edges per block in histogram/fill

typedef short frag8 __attribute__((ext_vector_type(8)));
typedef float f32x4 __attribute__((ext_vector_type(4)));
typedef unsigned long long u64;

static __device__ __forceinline__ unsigned short f2b(float f) {
    return __builtin_bit_cast(unsigned short, __float2bfloat16(f));
}
static __device__ __forceinline__ float h2f(unsigned short u) {
    return (float)__builtin_bit_cast(_Float16, u);
}

// ---------------- Kernel 0: W1 fp32 -> bf16, zero-padded to K=512 ----------------
__global__ __launch_bounds__(256) void k0_w1bf(const float* __restrict__ W1,
                                               unsigned short* __restrict__ W1bf)
{
    const int i = blockIdx.x * 256 + threadIdx.x;   // 0..32767
    const int c = i >> 9;        // col 0..63
    const int k = i & 511;
    const float v = (k < KD) ? W1[c * KD + k] : 0.f;
    W1bf[i] = f2b(v);
}

// ---------------- Kernel 1: h = relu(x @ W1^T), bf16 MFMA ----------------
// 512 threads = 8 waves; each wave computes 16 rows x 64 cols; block = 128 rows.
__global__ __launch_bounds__(512, 6) void k1_mfma(const float* __restrict__ x,
                                                  const unsigned short* __restrict__ W1bf,
                                                  float* __restrict__ h, int n)
{
    __shared__ unsigned short lw[64 * LWS];
    const int tid   = threadIdx.x;
    const int lane  = tid & 63;
    const int wid   = tid >> 6;      // 0..7
    const int l15   = lane & 15;
    const int l4    = lane >> 4;     // 0..3
    const int koffl = 8 * l4;        // lane's k sub-offset within a 32-k step

    const long rowBlk = (long)blockIdx.x * 128;
    long ra = rowBlk + wid * 16 + l15;
    if (ra >= n) ra = n - 1;                 // clamp; stores are guarded
    const float* xp = x + ra * KD + koffl;

    f32x4 acc[4] = {};
    const float4 z = make_float4(0.f, 0.f, 0.f, 0.f);

    for (int c = 0; c < 2; ++c) {
        if (c) __syncthreads();
        #pragma unroll
        for (int it = 0; it < 4; ++it) {
            const int idx = tid + it * 512;      // 0..2047
            const int r   = idx >> 5;            // 0..63
            const int q   = idx & 31;            // ushort8 index
            *(uint4*)&lw[r * LWS + q * 8] =
                *(const uint4*)&W1bf[r * KP + c * 256 + q * 8];
        }
        __syncthreads();

        int k0 = c * 256;
        float4 lo = (k0 + koffl     < KD) ? *(const float4*)(xp + k0)     : z;
        float4 hi = (k0 + koffl + 4 < KD) ? *(const float4*)(xp + k0 + 4) : z;

        #pragma unroll
        for (int ks = 0; ks < 8; ++ks) {
            float4 nlo = z, nhi = z;
            if (ks < 7) {
                const int kn = c * 256 + (ks + 1) * 32;
                nlo = (kn + koffl     < KD) ? *(const float4*)(xp + kn)     : z;
                nhi = (kn + koffl + 4 < KD) ? *(const float4*)(xp + kn + 4) : z;
            }
            frag8 a;
            a[0]=f2b(lo.x); a[1]=f2b(lo.y); a[2]=f2b(lo.z); a[3]=f2b(lo.w);
            a[4]=f2b(hi.x); a[5]=f2b(hi.y); a[6]=f2b(hi.z); a[7]=f2b(hi.w);
            const int koffw = ks * 32 + koffl;
            #pragma unroll
            for (int g = 0; g < 4; ++g) {
                const frag8 b = *(const frag8*)&lw[(g * 16 + l15) * LWS + koffw];
                acc[g] = __builtin_amdgcn_mfma_f32_16x16x32_bf16(a, b, acc[g], 0, 0, 0);
            }
            lo = nlo; hi = nhi;
        }
    }

    #pragma unroll
    for (int r = 0; r < 4; ++r) {
        const long row = rowBlk + wid * 16 + l4 * 4 + r;
        if (row < n) {
            #pragma unroll
            for (int g = 0; g < 4; ++g)
                h[row * HID + g * 16 + l15] = fmaxf(acc[g][r], 0.f);
        }
    }
}

// ---------------- Kernel 2: projections ----------------
// out = h @ WfA^T ; gpk[:,0:10) = fp16(h @ WfB^T) ; gpk[:,10:20) = fp16(h @ WfC^T)
__global__ __launch_bounds__(256) void k2_proj(const float* __restrict__ h,
                                               const float* __restrict__ Wf,
                                               float* __restrict__ out,
                                               _Float16* __restrict__ gpk, int n)
{
    __shared__ float lwf[10 * 196];
    const int tid = threadIdx.x;
    for (int idx = tid; idx < 480; idx += 256) {
        const int j = idx / 48;
        const int q = idx - j * 48;
        const float4 v = *(const float4*)&Wf[j * 192 + 4 * q];
        *(float4*)&lwf[j * 196 + 4 * q] = v;
    }
    __syncthreads();

    const long row = (long)blockIdx.x * 8 + (tid >> 5);
    const int  j   = tid & 31;
    if (row < n && j < 30) {
        const int wrow = (j < 10) ? j : ((j < 20) ? j - 10 : j - 20);
        const int coff = (j < 10) ? 0 : ((j < 20) ? 64 : 128);
        const float* wp = &lwf[wrow * 196 + coff];
        const float* hp = &h[row * HID];
        float s = 0.f;
        #pragma unroll
        for (int q = 0; q < 16; ++q) {
            const float4 hv = *(const float4*)&hp[4 * q];
            const float4 wv = *(const float4*)&wp[4 * q];
            s += hv.x * wv.x + hv.y * wv.y + hv.z * wv.z + hv.w * wv.w;
        }
        if (j < 10)      out[row * 10 + j] = s;
        else if (j < 20) gpk[row * GPS + (j - 10)]      = (_Float16)s;
        else             gpk[row * GPS + 10 + (j - 20)] = (_Float16)s;
    }
}

// ---------------- Kernel A: per-(chunk,bucket) edge histogram ----------------
__global__ __launch_bounds__(256) void kA_hist(const int* __restrict__ dst1, int nnz1,
                                               const int* __restrict__ dst2, int ntE,
                                               int* __restrict__ Cmat)
{
    __shared__ int cnt[NB];
    const int tid = threadIdx.x, blk = blockIdx.x;
    for (int i = tid; i < NB; i += 256) cnt[i] = 0;
    __syncthreads();
    const int base = blk * CHUNK;
    #pragma unroll
    for (int it = 0; it < CHUNK / 256; ++it) {
        const int id = base + it * 256 + tid;
        if (id < ntE) {
            const int d = (id < nnz1) ? __builtin_nontemporal_load(&dst1[id])
                                      : __builtin_nontemporal_load(&dst2[id - nnz1]);
            atomicAdd(&cnt[d / DB], 1);
        }
    }
    __syncthreads();
    for (int b = tid; b < NB; b += 256) Cmat[(size_t)blk * NB + b] = cnt[b];
}

// ---------------- Kernel S1: grouped bucket scan ----------------
// 16 buckets/block x 16 threads/bucket; coalesced. Slot order within a bucket
// is arbitrary (kD only sums), so strided per-thread chunk ownership is valid.
__global__ __launch_bounds__(256) void kS1_grp(const int* __restrict__ Cmat, int nblk,
                                               int* __restrict__ OFFmat,
                                               int* __restrict__ rowSum)
{
    __shared__ int lsum[256];
    const int tid = threadIdx.x;
    const int g   = tid >> 4;                  // group 0..15
    const int t   = tid & 15;                  // lane in group
    const int b   = blockIdx.x * 16 + g;       // bucket
    int s = 0;
    if (b < NB)
        for (int c = t; c < nblk; c += 16)
            s += Cmat[(size_t)c * NB + b];
    lsum[tid] = s;
    __syncthreads();
    int pre = 0;
    #pragma unroll
    for (int u = 0; u < 16; ++u) {
        const int v = lsum[(g << 4) + u];
        if (u < t) pre += v;
    }
    if (b < NB) {
        int run = pre;
        for (int c = t; c < nblk; c += 16) {
            OFFmat[(size_t)c * NB + b] = run;
            run += Cmat[(size_t)c * NB + b];
        }
        if (t == 15) rowSum[b] = run;
    }
}

// ---------------- Kernel S2: exclusive scan of bucket totals (13 elems/thread) --
__global__ __launch_bounds__(256) void kS2_basescan(const int* __restrict__ rowSum,
                                                    int* __restrict__ rowBase)
{
    __shared__ int ls[256];
    const int tid = threadIdx.x;
    const int EPT = (NB + 255) / 256;   // 13
    int e[13]; int s = 0;
    #pragma unroll
    for (int u = 0; u < 13; ++u) {
        const int i = tid * EPT + u;
        e[u] = (i < NB) ? rowSum[i] : 0;
        s += e[u];
    }
    ls[tid] = s;
    __syncthreads();
    for (int off = 1; off < 256; off <<= 1) {
        const int v = (tid >= off) ? ls[tid - off] : 0;
        __syncthreads();
        ls[tid] += v;
        __syncthreads();
    }
    int run = ls[tid] - s;
    #pragma unroll
    for (int u = 0; u < 13; ++u) {
        const int i = tid * EPT + u;
        if (i < NB) rowBase[i] = run;
        run += e[u];
    }
}

// ---------------- Kernel C: fill buckets with packed edge records ----------------
// rec = (src | hop<<17 | dstLocal<<18) | bitcast(val)<<32  -- one u64 store
__global__ __launch_bounds__(256) void kC_fill(const int* __restrict__ src1,
                                               const int* __restrict__ dst1,
                                               const float* __restrict__ val1, int nnz1,
                                               const int* __restrict__ src2,
                                               const int* __restrict__ dst2,
                                               const float* __restrict__ val2, int ntE,
                                               const int* __restrict__ OFFmat,
                                               const int* __restrict__ rowBase,
                                               u64* __restrict__ bins)
{
    __shared__ int cur[NB];
    const int tid = threadIdx.x, blk = blockIdx.x;
    for (int b = tid; b < NB; b += 256)
        cur[b] = rowBase[b] + OFFmat[(size_t)blk * NB + b];
    __syncthreads();
    const int base = blk * CHUNK;
    #pragma unroll
    for (int it = 0; it < CHUNK / 256; ++it) {
        const int id = base + it * 256 + tid;
        if (id < ntE) {
            const bool h1 = id < nnz1;
            const int  ii = h1 ? id : id - nnz1;
            const int   s = h1 ? __builtin_nontemporal_load(&src1[ii])
                               : __builtin_nontemporal_load(&src2[ii]);
            const int   d = h1 ? __builtin_nontemporal_load(&dst1[ii])
                               : __builtin_nontemporal_load(&dst2[ii]);
            const float v = h1 ? __builtin_nontemporal_load(&val1[ii])
                               : __builtin_nontemporal_load(&val2[ii]);
            const int   b = d / DB;
            const int slot = atomicAdd(&cur[b], 1);
            const unsigned lo = (unsigned)s | ((unsigned)(!h1) << 17)
                              | ((unsigned)(d - b * DB) << 18);
            const u64 r = (u64)lo | ((u64)__builtin_bit_cast(unsigned, v) << 32);
            __builtin_nontemporal_store(r, &bins[slot]);
        }
    }
}

// ---------------- Kernel D: per-EDGE threads, vectorized row gather --------------
// One thread per edge: 1x u64 record, 5x u32 gather (one line), 10 LDS atomics.
__global__ __launch_bounds__(256) void kD_acc(const u64* __restrict__ bins,
                                              const int* __restrict__ rowBase,
                                              const int* __restrict__ rowSum,
                                              const _Float16* __restrict__ gpk,
                                              float* __restrict__ out)
{
    __shared__ float lacc[DB * 10];
    const int tid = threadIdx.x, b = blockIdx.x;
    for (int i = tid; i < DB * 10; i += 256) lacc[i] = 0.f;
    __syncthreads();
    const int start = rowBase[b];
    const int nt    = rowSum[b];
    const unsigned* gp32 = (const unsigned*)gpk;

    for (int e0 = tid; e0 < nt; e0 += 512) {
        const bool ok1 = (e0 + 256) < nt;
        // two independent chains in flight
        const u64 r0 = __builtin_nontemporal_load(&bins[start + e0]);
        const u64 r1 = ok1 ? __builtin_nontemporal_load(&bins[start + e0 + 256]) : 0ULL;

        const unsigned lo0 = (unsigned)r0;
        const float    v0  = __builtin_bit_cast(float, (unsigned)(r0 >> 32));
        const int src0 = lo0 & 0x1FFFF;
        const int hop0 = (lo0 >> 17) & 1;
        const int dl0  = (int)(lo0 >> 18);
        const unsigned* g0 = gp32 + (size_t)src0 * (GPS / 2) + hop0 * 5;

        const unsigned lo1 = (unsigned)r1;
        const float    v1  = __builtin_bit_cast(float, (unsigned)(r1 >> 32));
        const int src1_ = lo1 & 0x1FFFF;
        const int hop1 = (lo1 >> 17) & 1;
        const int dl1  = (int)(lo1 >> 18);
        const unsigned* g1 = gp32 + (size_t)src1_ * (GPS / 2) + hop1 * 5;

        unsigned d0[5], d1[5];
        #pragma unroll
        for (int k = 0; k < 5; ++k) d0[k] = g0[k];
        if (ok1) {
            #pragma unroll
            for (int k = 0; k < 5; ++k) d1[k] = g1[k];
        }

        float* l0 = &lacc[dl0 * 10];
        #pragma unroll
        for (int k = 0; k < 5; ++k) {
            atomicAdd(&l0[2 * k],     v0 * h2f((unsigned short)d0[k]));
            atomicAdd(&l0[2 * k + 1], v0 * h2f((unsigned short)(d0[k] >> 16)));
        }
        if (ok1) {
            float* l1 = &lacc[dl1 * 10];
            #pragma unroll
            for (int k = 0; k < 5; ++k) {
                atomicAdd(&l1[2 * k],     v1 * h2f((unsigned short)d1[k]));
                atomicAdd(&l1[2 * k + 1], v1 * h2f((unsigned short)(d1[k] >> 16)));
            }
        }
    }
    __syncthreads();
    float* op = out + (size_t)b * DB * 10;
    for (int i = tid; i < DB * 10; i += 256) {
        const float v = __builtin_nontemporal_load(&op[i]) + lacc[i];
        __builtin_nontemporal_store(v, &op[i]);
    }
}

// ---------------- Fallback: direct scatter (agent-scope atomics) ----------------
__global__ __launch_bounds__(256) void k_scatter_dir(const int* __restrict__ src1,
                                                     const int* __restrict__ dst1,
                                                     const float* __restrict__ val1, int n1,
                                                     const int* __restrict__ src2,
                                                     const int* __restrict__ dst2,
                                                     const float* __restrict__ val2, int nt,
                                                     const _Float16* __restrict__ gpk,
                                                     float* __restrict__ out)
{
    const int t = blockIdx.x * 256 + threadIdx.x;
    if (t >= nt) return;
    const bool h1 = t < n1;
    const int  tt = h1 ? t : t - n1;
    const int  e  = (int)((unsigned)tt / 10u);
    const int  j  = tt - 10 * e;
    const int* sp = h1 ? src1 : src2;
    const int* dp = h1 ? dst1 : dst2;
    const float* vp = h1 ? val1 : val2;
    unsafeAtomicAdd(&out[(size_t)dp[e] * 10 + j],
                    vp[e] * (float)gpk[(size_t)sp[e] * GPS + (h1 ? 0 : 10) + j]);
}

extern "C" void kernel_launch(void* const* d_in, const int* in_sizes, int n_in,
                              void* d_out, int out_size, void* d_ws, size_t ws_size,
                              hipStream_t stream)
{
    const float* x    = (const float*)d_in[0];
    const float* W1   = (const float*)d_in[1];
    const float* Wf   = (const float*)d_in[2];
    const int*   src1 = (const int*)d_in[3];
    const int*   dst1 = (const int*)d_in[4];
    const float* val1 = (const float*)d_in[5];
    const int*   src2 = (const int*)d_in[6];
    const int*   dst2 = (const int*)d_in[7];
    const float* val2 = (const float*)d_in[8];
    const int nnz1 = in_sizes[3];
    const int nnz2 = in_sizes[6];
    const int ntE  = nnz1 + nnz2;
    const int n = NN;
    const int nblk = (ntE + CHUNK - 1) / CHUNK;

    char* p = (char*)d_ws;
    unsigned short* W1bf = (unsigned short*)p;       p += (size_t)64 * KP * 2;   // 64 KB
    float* h      = (float*)p;                       p += (size_t)NN * HID * 4;  // 25.6 MB
    _Float16* gpk = (_Float16*)p;                    p += (size_t)NN * GPS * 2;  //  4.0 MB
    u64* bins     = (u64*)p;                         p += (size_t)ntE * 8;       // 14.4 MB
    int* Cmat     = (int*)p;                         p += (size_t)NB * nblk * 4; //  5.5 MB
    int* OFFmat   = (int*)p;                         p += (size_t)NB * nblk * 4; //  5.5 MB
    int* rowSum   = (int*)p;                         p += (size_t)NB * 4;
    int* rowBase  = (int*)p;                         p += (size_t)NB * 4;
    float* out    = (float*)d_out;                   // [NN][10]
    const size_t ws_need = (size_t)(p - (char*)d_ws);

    k0_w1bf<<<128, 256, 0, stream>>>(W1, W1bf);
    k1_mfma<<<(n + 127) / 128, 512, 0, stream>>>(x, W1bf, h, n);
    k2_proj<<<(n + 7) / 8, 256, 0, stream>>>(h, Wf, out, gpk, n);

    if (ws_size >= ws_need) {
        kA_hist<<<nblk, 256, 0, stream>>>(dst1, nnz1, dst2, ntE, Cmat);
        kS1_grp<<<(NB + 15) / 16, 256, 0, stream>>>(Cmat, nblk, OFFmat, rowSum);
        kS2_basescan<<<1, 256, 0, stream>>>(rowSum, rowBase);
        kC_fill<<<nblk, 256, 0, stream>>>(src1, dst1, val1, nnz1,
                                          src2, dst2, val2, ntE,
                                          OFFmat, rowBase, bins);
        kD_acc<<<NB, 256, 0, stream>>>(bins, rowBase, rowSum, gpk, out);
    } else {
        const int n1 = 10 * nnz1;
        const int nt = n1 + 10 * nnz2;
        k_scatter_dir<<<(nt + 255) / 256, 256, 0, stream>>>(src1, dst1, val1, n1,
                                                            src2, dst2, val2, nt,
                                                            gpk, out);
    }
}